// Round 8
// baseline (2042.731 us; speedup 1.0000x reference)
//
#include <hip/hip_runtime.h>
#include <hip/hip_bf16.h>
#include <hip/hip_fp16.h>

typedef __attribute__((ext_vector_type(8))) short short8;
typedef __attribute__((ext_vector_type(4))) float f32x4;
typedef __attribute__((ext_vector_type(4))) unsigned int u32x4;

#define Hh 512
#define Bb 64
#define Ss 512
#define Gg 2048
#define NROW 32768

static __device__ inline short f2bf(float f) {
    union { float f; unsigned u; } v; v.f = f;
    unsigned r = (v.u + 0x7FFFu + ((v.u >> 16) & 1u)) >> 16;
    return (short)r;
}

static __device__ inline short8 pack_bf8(const float* p) {
    f32x4 u0 = *(const f32x4*)p;
    f32x4 u1 = *(const f32x4*)(p + 4);
    short8 t;
    t[0] = f2bf(u0[0]); t[1] = f2bf(u0[1]); t[2] = f2bf(u0[2]); t[3] = f2bf(u0[3]);
    t[4] = f2bf(u1[0]); t[5] = f2bf(u1[1]); t[6] = f2bf(u1[2]); t[7] = f2bf(u1[3]);
    return t;
}

static __device__ inline float fsigmoid(float x) {
    return __builtin_amdgcn_rcpf(1.f + __builtin_amdgcn_exp2f(x * -1.44269504088896f));
}
static __device__ inline float ftanh(float x) {
    float xc = fminf(fmaxf(x, -15.f), 15.f);
    float e = __builtin_amdgcn_exp2f(xc * 2.88539008177793f); // e^(2x)
    return (e - 1.f) / (e + 1.f);
}

// ---------------- prep: f32 -> bf16 for W_ih and fc_W ----------------
__global__ __launch_bounds__(256)
void prep_bf16(const float* __restrict__ wih, const float* __restrict__ fcw,
               short* __restrict__ wih_bf, short* __restrict__ fcw_bf) {
    const int n1 = Gg * 256;
    const int n2 = 48 * Hh;
    for (int i = blockIdx.x * blockDim.x + threadIdx.x; i < n1 + n2;
         i += gridDim.x * blockDim.x) {
        if (i < n1) wih_bf[i] = f2bf(wih[i]);
        else        fcw_bf[i - n1] = f2bf(fcw[i - n1]);
    }
}

// ---------------- prep: xe[r][k] = bf16(emb[x[r]][k]),  r = b*S + s ----------------
__global__ __launch_bounds__(256)
void prep_xe(const int* __restrict__ x, const float* __restrict__ emb,
             short* __restrict__ xe) {
    const long i = ((long)blockIdx.x * 256 + threadIdx.x) * 8;   // element index
    const int row = (int)(i >> 8);
    const int col = (int)(i & 255);
    const int tok = x[row];
    *(short8*)(xe + i) = pack_bf8(emb + (long)tok * 256 + col);
}

// ---------------- persistent LSTM recurrence with folded input projection ----------------
// 32 WGs x 512 thr. cluster cl = blockIdx&3 (16 batches), wgc = blockIdx>>2 (64 cols).
// Pre-poll (off critical chain): acc = b_hh + xe_t @ W_ih^T  (xe + W_ih streamed, 16 MFMA).
// Then R7's proven exchange: per-wave flag poll -> one-round-trip staging -> h MFMAs.
__global__ __launch_bounds__(512)
void lstm_kernel(const float* __restrict__ whh, const short* __restrict__ xe,
                 const short* __restrict__ wih_bf, const float* __restrict__ bhh,
                 unsigned int* __restrict__ hbuf32,   // [2][64][256] packed bf16x2
                 unsigned int* __restrict__ hs32,     // [32768][256] packed bf16x2
                 int* __restrict__ flags) {           // [4][32] ints
    const int cl  = blockIdx.x & 3;
    const int wgc = blockIdx.x >> 2;       // 0..7
    const int b0 = cl * 16;
    const int J0 = wgc * 64;
    const int tid = threadIdx.x;
    const int w = tid >> 6;                // 0..7
    const int lane = tid & 63;
    const int lr = lane & 15, lc = lane >> 4;
    const int gt = w & 3;
    const int Jsub = (w >> 2) * 32;

    __shared__ float gates[4][16][66];                     // padded
    __shared__ __align__(16) unsigned int hlds[16 * 256];  // 16 KB, sigma-swizzled

    // W_hh fragments resident: 2 tiles x 16 k-steps (128 regs)
    short8 wf[2][16];
#pragma unroll
    for (int u = 0; u < 2; u++)
#pragma unroll
        for (int ks = 0; ks < 16; ks++)
            wf[u][ks] = pack_bf8(whh + (long)(gt * Hh + J0 + Jsub + u * 16 + lr) * Hh + ks * 32 + lc * 8);

    // cell state in registers: thread owns (eb, 2*jp), (eb, 2*jp+1)
    const int eb = tid >> 5;               // 0..15
    const int jp = tid & 31;
    float c0 = 0.f, c1 = 0.f;

    const int gr0 = gt * Hh + J0 + Jsub + lr;
    const float bias0 = bhh[gr0], bias1 = bhh[gr0 + 16];

    // staging geometry: thread -> (row = tid>>5, colgroup = tid&31), 32B each.
    const int srow = tid >> 5;
    const int scg  = tid & 31;
    const int q0c  = 2 * scg;
    const int chi0 = (q0c ^ ((q0c >> 3) & 7) ^ (srow & 7));
    const int sidx0 = srow * 256 + chi0 * 4;
    const int sidx1 = srow * 256 + (chi0 ^ 1) * 4;

    int* const myflag = flags + cl * 32 + wgc;
    const int* const pollbase = flags + cl * 32;

    const short* const xerow = xe + ((long)(b0 + lr) * Ss) * 256 + lc * 8;
    const short* const wrow0 = wih_bf + (long)gr0 * 256 + lc * 8;
    const short* const wrow1 = wih_bf + (long)(gr0 + 16) * 256 + lc * 8;

#pragma unroll 1
    for (int t = 0; t < Ss; t++) {
        // ---------- pre-poll, off-chain: acc = bias + xe_t @ W_ih^T ----------
        short8 xef[8];
#pragma unroll
        for (int ks = 0; ks < 8; ks++)
            xef[ks] = *(const short8*)(xerow + (long)t * 256 + ks * 32);

        f32x4 acc0, acc1;
#pragma unroll
        for (int i = 0; i < 4; i++) { acc0[i] = bias0; acc1[i] = bias1; }
#pragma unroll
        for (int ks = 0; ks < 8; ks++) {
            const short8 w0 = *(const short8*)(wrow0 + ks * 32);
            const short8 w1 = *(const short8*)(wrow1 + ks * 32);
            acc0 = __builtin_amdgcn_mfma_f32_16x16x32_bf16(xef[ks], w0, acc0, 0, 0, 0);
            acc1 = __builtin_amdgcn_mfma_f32_16x16x32_bf16(xef[ks], w1, acc1, 0, 0, 0);
        }

        // ---------- exchange: poll + one-round-trip staging (R7 protocol) ----------
        if (t == 0) {
            u32x4 z = {0u, 0u, 0u, 0u};
            *(u32x4*)&hlds[sidx0] = z;
            *(u32x4*)&hlds[sidx1] = z;
        } else {
            const int* fp = pollbase + (lane & 7);
            int fv = __hip_atomic_load(fp, __ATOMIC_RELAXED, __HIP_MEMORY_SCOPE_AGENT);
            while (__any(fv < t))
                fv = __hip_atomic_load(fp, __ATOMIC_RELAXED, __HIP_MEMORY_SCOPE_AGENT);
            asm volatile("" ::: "memory");
            const unsigned long long* hb = (const unsigned long long*)
                (hbuf32 + (t & 1) * (Bb * Hh / 2) + (b0 + srow) * 256 + scg * 8);
            unsigned long long a0 = __hip_atomic_load(hb + 0, __ATOMIC_RELAXED, __HIP_MEMORY_SCOPE_AGENT);
            unsigned long long a1 = __hip_atomic_load(hb + 1, __ATOMIC_RELAXED, __HIP_MEMORY_SCOPE_AGENT);
            unsigned long long a2 = __hip_atomic_load(hb + 2, __ATOMIC_RELAXED, __HIP_MEMORY_SCOPE_AGENT);
            unsigned long long a3 = __hip_atomic_load(hb + 3, __ATOMIC_RELAXED, __HIP_MEMORY_SCOPE_AGENT);
            u32x4 v0 = {(unsigned)a0, (unsigned)(a0 >> 32), (unsigned)a1, (unsigned)(a1 >> 32)};
            u32x4 v1 = {(unsigned)a2, (unsigned)(a2 >> 32), (unsigned)a3, (unsigned)(a3 >> 32)};
            *(u32x4*)&hlds[sidx0] = v0;
            *(u32x4*)&hlds[sidx1] = v1;
        }
        __syncthreads();   // A: h tile staged

#pragma unroll
        for (int ks = 0; ks < 16; ks++) {
            const int q = ks * 4 + lc;
            const int chi = q ^ ((q >> 3) & 7) ^ (lr & 7);
            const short8 af = *(const short8*)&hlds[lr * 256 + chi * 4];
            acc0 = __builtin_amdgcn_mfma_f32_16x16x32_bf16(af, wf[0][ks], acc0, 0, 0, 0);
            acc1 = __builtin_amdgcn_mfma_f32_16x16x32_bf16(af, wf[1][ks], acc1, 0, 0, 0);
        }

#pragma unroll
        for (int i = 0; i < 4; i++) {
            gates[gt][lc * 4 + i][Jsub + lr]      = acc0[i];
            gates[gt][lc * 4 + i][Jsub + 16 + lr] = acc1[i];
        }
        __syncthreads();   // B: gates ready

        unsigned hpack;
        {
            const float2 gI = *(const float2*)&gates[0][eb][jp * 2];
            const float2 gF = *(const float2*)&gates[1][eb][jp * 2];
            const float2 gG = *(const float2*)&gates[2][eb][jp * 2];
            const float2 gO = *(const float2*)&gates[3][eb][jp * 2];
            c0 = fsigmoid(gF.x) * c0 + fsigmoid(gI.x) * ftanh(gG.x);
            c1 = fsigmoid(gF.y) * c1 + fsigmoid(gI.y) * ftanh(gG.y);
            const float h0 = fsigmoid(gO.x) * ftanh(c0);
            const float h1 = fsigmoid(gO.y) * ftanh(c1);
            hpack = (unsigned)(unsigned short)f2bf(h0)
                  | ((unsigned)(unsigned short)f2bf(h1) << 16);
            unsigned int* hw = hbuf32 + ((t + 1) & 1) * (Bb * Hh / 2)
                               + (b0 + eb) * 256 + (J0 >> 1) + jp;
            __hip_atomic_store(hw, hpack, __ATOMIC_RELAXED, __HIP_MEMORY_SCOPE_AGENT);
        }
        __syncthreads();   // C: all h stores drained (vmcnt0 before barrier)
        if (tid == 0)
            __hip_atomic_store(myflag, t + 1, __ATOMIC_RELAXED, __HIP_MEMORY_SCOPE_AGENT);

        // off the critical path: history store
        hs32[((long)(b0 + eb) * Ss + t) * 256 + (J0 >> 1) + jp] = hpack;
    }
}

// ---------------- logits = hs @ fc_W^T + fc_b, then log_softmax ----------------
__global__ __launch_bounds__(256)
void fc_kernel(const unsigned short* __restrict__ hs, const short* __restrict__ fcw_bf,
               const float* __restrict__ fcb, float* __restrict__ out) {
    const int w = threadIdx.x >> 6, lane = threadIdx.x & 63;
    const int lr = lane & 15, lc = lane >> 4;
    const int r0 = blockIdx.x * 64 + w * 16;

    short8 af[16];
#pragma unroll
    for (int ks = 0; ks < 16; ks++)
        af[ks] = *(const short8*)((const short*)hs + (long)(r0 + lr) * Hh + ks * 32 + lc * 8);

    f32x4 acc[3];
#pragma unroll
    for (int nt = 0; nt < 3; nt++) {
        f32x4 a_ = {0.f, 0.f, 0.f, 0.f};
#pragma unroll
        for (int ks = 0; ks < 16; ks++) {
            short8 b = *(const short8*)(fcw_bf + (nt * 16 + lr) * Hh + ks * 32 + lc * 8);
            a_ = __builtin_amdgcn_mfma_f32_16x16x32_bf16(af[ks], b, a_, 0, 0, 0);
        }
        acc[nt] = a_;
    }

    const float bb0 = fcb[lr], bb1 = fcb[16 + lr], bb2 = fcb[32 + lr];
#pragma unroll
    for (int i = 0; i < 4; i++) {
        float v0 = acc[0][i] + bb0, v1 = acc[1][i] + bb1, v2 = acc[2][i] + bb2;
        float m = fmaxf(v0, fmaxf(v1, v2));
#pragma unroll
        for (int d = 1; d < 16; d <<= 1) m = fmaxf(m, __shfl_xor(m, d));
        float s = expf(v0 - m) + expf(v1 - m) + expf(v2 - m);
#pragma unroll
        for (int d = 1; d < 16; d <<= 1) s += __shfl_xor(s, d);
        const float lse = m + logf(s);
        const long r = r0 + lc * 4 + i;
        out[r * 48 + lr]      = v0 - lse;
        out[r * 48 + 16 + lr] = v1 - lse;
        out[r * 48 + 32 + lr] = v2 - lse;
    }
}

extern "C" void kernel_launch(void* const* d_in, const int* in_sizes, int n_in,
                              void* d_out, int out_size, void* d_ws, size_t ws_size,
                              hipStream_t stream) {
    const int*   x   = (const int*)d_in[0];
    const float* emb = (const float*)d_in[1];
    const float* wih = (const float*)d_in[2];
    const float* whh = (const float*)d_in[3];
    const float* bhh = (const float*)d_in[4];
    const float* fcw = (const float*)d_in[5];
    const float* fcb = (const float*)d_in[6];
    float* out = (float*)d_out;

    char* ws = (char*)d_ws;
    const size_t off_xe    = 0;                                     // 16.8 MB used
    const size_t off_hs    = (size_t)NROW * Gg * 2;                 // keep legacy layout
    const size_t off_hbuf  = off_hs + (size_t)NROW * Hh * 2;
    const size_t off_flags = off_hbuf + 2 * (size_t)Bb * Hh * 2;
    const size_t off_wih   = off_flags + 4096;
    const size_t off_fcw   = off_wih + (size_t)Gg * 256 * 2;

    short*        xe     = (short*)(ws + off_xe);
    unsigned int* hs32   = (unsigned int*)(ws + off_hs);
    unsigned int* hbuf32 = (unsigned int*)(ws + off_hbuf);
    int*          flags  = (int*)(ws + off_flags);
    short*        wih_bf = (short*)(ws + off_wih);
    short*        fcw_bf = (short*)(ws + off_fcw);

    hipMemsetAsync(flags, 0, 4096, stream);
    prep_bf16<<<512, 256, 0, stream>>>(wih, fcw, wih_bf, fcw_bf);
    prep_xe<<<4096, 256, 0, stream>>>(x, emb, xe);

    void* args[] = {(void*)&whh, (void*)&xe, (void*)&wih_bf, (void*)&bhh,
                    (void*)&hbuf32, (void*)&hs32, (void*)&flags};
    hipLaunchCooperativeKernel((void*)lstm_kernel, dim3(32), dim3(512), args, 0, stream);

    fc_kernel<<<512, 256, 0, stream>>>((const unsigned short*)hs32, fcw_bf, fcb, out);
}